// Round 8
// baseline (721.005 us; speedup 1.0000x reference)
//
#include <hip/hip_runtime.h>
#include <cstdint>
#include <cstddef>

#define D       512
#define NROWS   16384
#define NCODES  8192
#define BM      128
#define BN      128
#define BK      32
#define NKC     (D / BK)        // 16
#define RB      (NROWS / BM)    // 128
#define CB      (NCODES / BN)   // 64
#define NBLK    (RB * CB)       // 8192
#define EPS     0.02f
#define RCB     1024
#define TILE_BYTES 16384        // per (blk,kc): [HI 8KB][LO 8KB]

typedef __attribute__((ext_vector_type(8))) short short8;  // 8 bf16
typedef __attribute__((ext_vector_type(4))) float f32x4;
typedef unsigned long long u64;
typedef __attribute__((address_space(3))) uint32_t as3_u32;
typedef __attribute__((address_space(1))) uint32_t as1_u32;

// order-preserving fp32 <-> u32 key
__device__ __forceinline__ uint32_t fkey(float f) {
  uint32_t u = __float_as_uint(f);
  return (u & 0x80000000u) ? ~u : (u | 0x80000000u);
}
__device__ __forceinline__ float unfkey(uint32_t k) {
  uint32_t u = (k & 0x80000000u) ? (k & 0x7FFFFFFFu) : ~k;
  return __uint_as_float(u);
}
// round-to-nearest bf16, returned as high-aligned fp32 bits
__device__ __forceinline__ uint32_t bfhi(float f) {
  uint32_t u = __float_as_uint(f);
  return (u + 0x7FFFu + ((u >> 16) & 1u)) & 0xFFFF0000u;
}

// ---------------------------------------------------------------------------
// Fused pre-pack (x AND embed) + e2.
// fp32 [rows][512] -> bf16 hi/lo planes in tile-kc order, swizzled chunk
// cp = c ^ ((r>>1)&3) for conflict-free b128 LDS frag reads.
// The 64 chunk-threads of one row are exactly one wave -> e2 = free butterfly.
// Grid covers x chunks then embed chunks (block-aligned split).
// ---------------------------------------------------------------------------
__global__ __launch_bounds__(256) void vq_pack_kernel(
    const float* __restrict__ x, const float* __restrict__ embed,
    uint32_t* __restrict__ px, uint32_t* __restrict__ pe,
    float* __restrict__ e2) {
  const int t   = blockIdx.x * 256 + threadIdx.x;   // global chunk id
  const bool isX = t < NROWS * 64;                  // uniform per block
  const int tt  = isX ? t : t - NROWS * 64;
  const float* src  = isX ? x : embed;
  uint32_t*    dst  = isX ? px : pe;

  const int row = tt >> 6;
  const int q   = tt & 63;
  const int kc  = q >> 2, c = q & 3;
  const int blk = row >> 7, r = row & 127;
  const int cp  = c ^ ((r >> 1) & 3);

  const float* sp = src + (size_t)row * D + kc * 32 + c * 8;
  const float4 v0 = *(const float4*)sp;
  const float4 v1 = *(const float4*)(sp + 4);
  const float f[8] = {v0.x, v0.y, v0.z, v0.w, v1.x, v1.y, v1.z, v1.w};
  uint32_t hi[4], lo[4];
  float ss = 0.f;
#pragma unroll
  for (int p = 0; p < 4; ++p) {
    const uint32_t h0 = bfhi(f[2 * p]), h1 = bfhi(f[2 * p + 1]);
    hi[p] = (h0 >> 16) | (h1 & 0xFFFF0000u);
    const float l0 = f[2 * p] - __uint_as_float(h0);
    const float l1 = f[2 * p + 1] - __uint_as_float(h1);
    lo[p] = (bfhi(l0) >> 16) | (bfhi(l1) & 0xFFFF0000u);
    ss += f[2 * p] * f[2 * p] + f[2 * p + 1] * f[2 * p + 1];
  }
  uint32_t* dp = dst + (size_t)(blk * NKC + kc) * (TILE_BYTES / 4) + r * 16 + cp * 4;
  *(uint4*)dp          = make_uint4(hi[0], hi[1], hi[2], hi[3]);   // HI plane
  *(uint4*)(dp + 2048) = make_uint4(lo[0], lo[1], lo[2], lo[3]);   // LO plane

  if (!isX) {   // e2: butterfly across the row's wave
#pragma unroll
    for (int m = 32; m >= 1; m >>= 1) ss += __shfl_xor(ss, m, 64);
    if ((tt & 63) == 0) e2[row] = ss;
  }
}

// ---------------------------------------------------------------------------
// MFMA distance kernel on pre-packed bf16 planes — 2-phase double-buffer.
// 128x128 tile, 4 waves (wave tile 64x64), BK=32, 2 x 32 KB LDS buffers
// -> 2 blocks/CU.  STAGE(t+1) issued BEFORE computing tile t; one
// __syncthreads per tile (drains vmcnt) — load latency hides under MFMA.
// 3-term split GEMM: hh + hl + lh. Exact global top-2 via atomicMin protocol.
// ---------------------------------------------------------------------------
__global__ __launch_bounds__(256) void vq_mfma_kernel(
    const uint32_t* __restrict__ xp, const uint32_t* __restrict__ ep,
    const float* __restrict__ e2g,
    u64* __restrict__ min1g, u64* __restrict__ min2g) {
  __shared__ __align__(16) char smem[65536];
  // buffer b at smem + b*32768: [0,8K) XH | [8K,16K) XL | [16K,24K) EH | [24K,32K) EL

  const int tid  = threadIdx.x;
  const int lane = tid & 63;
  const int w    = tid >> 6;          // 0..3
  const int wr   = (w >> 1) * 64;
  const int wcI  = w & 1;
  const int wc   = wcI * 64;

  // XCD swizzle: 8 cb per XCD; cb fast-varying -> x-tile L2 reuse across cbs
  const int xcd = blockIdx.x & 7;
  const int id  = blockIdx.x >> 3;     // 0..1023
  const int cb  = xcd * 8 + (id & 7);  // 0..63
  const int rb  = id >> 3;             // 0..127
  const int row0 = rb * BM;
  const int c0   = cb * BN;

  const char* xtile = (const char*)xp + (size_t)rb * NKC * TILE_BYTES;
  const char* etile = (const char*)ep + (size_t)cb * NKC * TILE_BYTES;

  f32x4 acc[4][4];
#pragma unroll
  for (int i = 0; i < 4; ++i)
#pragma unroll
    for (int j = 0; j < 4; ++j) acc[i][j] = (f32x4)0.f;

  const int fr = lane & 15;
  const int cl = lane >> 4;
  const int cs = (cl ^ ((fr >> 1) & 3)) * 16;  // swizzled k-quarter byte off

#define STAGE(kc, b)                                                          \
  do {                                                                        \
    const char* gx = xtile + (kc) * TILE_BYTES + tid * 16;                    \
    const char* ge = etile + (kc) * TILE_BYTES + tid * 16;                    \
    char* lb = smem + (b) * 32768 + tid * 16;                                 \
    _Pragma("unroll") for (int s = 0; s < 4; ++s) {                           \
      __builtin_amdgcn_global_load_lds(                                       \
          (const as1_u32*)(const void*)(gx + s * 4096),                       \
          (as3_u32*)(void*)(lb + s * 4096), 16, 0, 0);                        \
      __builtin_amdgcn_global_load_lds(                                       \
          (const as1_u32*)(const void*)(ge + s * 4096),                       \
          (as3_u32*)(void*)(lb + 16384 + s * 4096), 16, 0, 0);                \
    }                                                                         \
  } while (0)

  STAGE(0, 0);
  __syncthreads();                      // buf0 resident

  int cur = 0;
  for (int kc = 0; kc < NKC; ++kc) {
    if (kc + 1 < NKC) STAGE(kc + 1, cur ^ 1);   // in flight under MFMA

    const char* sb = smem + cur * 32768;
    short8 bh[4], bl[4];
#pragma unroll
    for (int j = 0; j < 4; ++j) {
      const int rbrow = wc + j * 16 + fr;
      bh[j] = *(const short8*)(sb + 16384 + rbrow * 64 + cs);
      bl[j] = *(const short8*)(sb + 24576 + rbrow * 64 + cs);
    }
#pragma unroll
    for (int i = 0; i < 4; ++i) {
      const int arow = wr + i * 16 + fr;
      const short8 ah = *(const short8*)(sb + arow * 64 + cs);
      const short8 al = *(const short8*)(sb + 8192 + arow * 64 + cs);
#pragma unroll
      for (int j = 0; j < 4; ++j) {
        acc[i][j] = __builtin_amdgcn_mfma_f32_16x16x32_bf16(ah, bh[j], acc[i][j], 0, 0, 0);
        acc[i][j] = __builtin_amdgcn_mfma_f32_16x16x32_bf16(ah, bl[j], acc[i][j], 0, 0, 0);
        acc[i][j] = __builtin_amdgcn_mfma_f32_16x16x32_bf16(al, bh[j], acc[i][j], 0, 0, 0);
      }
    }
    __syncthreads();   // next-tile loads drained (vmcnt 0); reads of cur done
    cur ^= 1;
  }
#undef STAGE

  // ---- epilogue: per-row top-2 over this block's 128 codes ----
  float e2v[4];
#pragma unroll
  for (int j = 0; j < 4; ++j) e2v[j] = e2g[c0 + wc + j * 16 + fr];

  u64 (*mb)[2][2] = (u64(*)[2][2])smem;  // [128 rows][wcIdx][min1,min2]

#pragma unroll
  for (int i = 0; i < 4; ++i) {
#pragma unroll
    for (int r = 0; r < 4; ++r) {
      float v1 = 3.4e38f, v2 = 3.4e38f;
      int c1 = 0;
#pragma unroll
      for (int j = 0; j < 4; ++j) {
        const float s = fmaf(-2.f, acc[i][j][r], e2v[j]);
        if (s < v1) { v2 = v1; v1 = s; c1 = c0 + wc + j * 16 + fr; }
        else if (s < v2) v2 = s;
      }
      u64 p1 = ((u64)fkey(v1) << 32) | (uint32_t)c1;
      uint32_t k2 = fkey(v2);
#pragma unroll
      for (int m = 8; m >= 1; m >>= 1) {   // merge across 16-lane row-group
        const u64 o1 = __shfl_xor(p1, m, 64);
        const uint32_t o2 = __shfl_xor(k2, m, 64);
        const u64 lo_ = p1 < o1 ? p1 : o1;
        const u64 hi_ = p1 < o1 ? o1 : p1;
        uint32_t nk = k2 < o2 ? k2 : o2;
        const uint32_t hk = (uint32_t)(hi_ >> 32);
        k2 = nk < hk ? nk : hk;
        p1 = lo_;
      }
      if ((lane & 15) == 0) {
        const int lrow = wr + i * 16 + (lane >> 4) * 4 + r;
        mb[lrow][wcI][0] = p1;
        mb[lrow][wcI][1] = ((u64)k2 << 32) | 0xFFFFFFFFull;
      }
    }
  }
  __syncthreads();

  if (tid < BM) {
    u64 m1 = mb[tid][0][0], m2 = mb[tid][0][1];
    const u64 a1 = mb[tid][1][0], a2 = mb[tid][1][1];
    const u64 nm1 = m1 < a1 ? m1 : a1;
    const u64 big = m1 < a1 ? a1 : m1;
    u64 nm2 = m2 < a2 ? m2 : a2;
    nm2 = nm2 < big ? nm2 : big;
    // lock-free global top-2 merge
    const u64 old = atomicMin(&min1g[row0 + tid], nm1);
    u64 push = nm1 < old ? old : nm1;       // max(m1, old)
    push = nm2 < push ? nm2 : push;
    atomicMin(&min2g[row0 + tid], push);
  }
}

// ---------------------------------------------------------------------------
__global__ __launch_bounds__(256) void vq_flag_kernel(
    const u64* __restrict__ min1g, const u64* __restrict__ min2g,
    int* __restrict__ count, int* __restrict__ list) {
  const int row = blockIdx.x * 256 + threadIdx.x;
  const float f1 = unfkey((uint32_t)(min1g[row] >> 32));
  const float f2 = unfkey((uint32_t)(min2g[row] >> 32));
  if (!(f2 - f1 >= EPS)) {              // also catches NaN
    const int p = atomicAdd(count, 1);
    list[p] = row;
  }
}

// ---------------------------------------------------------------------------
__global__ __launch_bounds__(256) void vq_exact_kernel(
    const float* __restrict__ x, const float* __restrict__ embed,
    const float* __restrict__ e2g, const int* __restrict__ count,
    const int* __restrict__ list, u64* __restrict__ min1g) {
  const int nItems = (*count) * 32;
  __shared__ u64 wbest[4];
  const int lane = threadIdx.x & 63;
  const int wv   = threadIdx.x >> 6;

  for (int it = blockIdx.x; it < nItems; it += RCB) {
    const int row   = list[it >> 5];
    const int cbase = (it & 31) * 256 + wv * 64;

    const float* xp = x + (size_t)row * D + lane * 8;
    const float4 xa = *(const float4*)xp;
    const float4 xb = *(const float4*)(xp + 4);

    float bv = 3.4e38f;
    int   bi = 0;
    for (int i = 0; i < 64; ++i) {
      const int c = cbase + i;
      const float* epr = embed + (size_t)c * D + lane * 8;
      const float4 ea = *(const float4*)epr;
      const float4 eb = *(const float4*)(epr + 4);
      float p = xa.x * ea.x + xa.y * ea.y + xa.z * ea.z + xa.w * ea.w +
                xb.x * eb.x + xb.y * eb.y + xb.z * eb.z + xb.w * eb.w;
#pragma unroll
      for (int m = 32; m >= 1; m >>= 1) p += __shfl_xor(p, m, 64);
      const float s = fmaf(-2.f, p, e2g[c]);
      if (s < bv) { bv = s; bi = c; }
    }
    const u64 pk = ((u64)fkey(bv) << 32) | (uint32_t)bi;
    if (lane == 0) wbest[wv] = pk;
    __syncthreads();
    if (threadIdx.x == 0) {
      u64 m = wbest[0];
#pragma unroll
      for (int q = 1; q < 4; ++q) m = wbest[q] < m ? wbest[q] : m;
      atomicMin(&min1g[row], m);
    }
    __syncthreads();
  }
}

// ---------------------------------------------------------------------------
__global__ void vq_finish_kernel(const float* __restrict__ x,
                                 const float* __restrict__ embed,
                                 const u64* __restrict__ min1g,
                                 float* __restrict__ out_q,
                                 float* __restrict__ out_idx,
                                 float* __restrict__ out_loss) {
  const int row  = blockIdx.x * 4 + (threadIdx.x >> 6);
  const int lane = threadIdx.x & 63;
  const int idx  = (int)(min1g[row] & 0xFFFFFFFFull);
  if (lane == 0) out_idx[row] = (float)idx;

  const float* ep = embed + (size_t)idx * D + lane * 8;
  const float* xp = x + (size_t)row * D + lane * 8;
  float* qp       = out_q + (size_t)row * D + lane * 8;

  const float4 e0 = *(const float4*)ep;
  const float4 e1 = *(const float4*)(ep + 4);
  const float4 x0 = *(const float4*)xp;
  const float4 x1 = *(const float4*)(xp + 4);
  *(float4*)qp       = e0;   // x + sg(q - x) == q numerically
  *(float4*)(qp + 4) = e1;

  float l = (e0.x - x0.x) * (e0.x - x0.x) + (e0.y - x0.y) * (e0.y - x0.y) +
            (e0.z - x0.z) * (e0.z - x0.z) + (e0.w - x0.w) * (e0.w - x0.w) +
            (e1.x - x1.x) * (e1.x - x1.x) + (e1.y - x1.y) * (e1.y - x1.y) +
            (e1.z - x1.z) * (e1.z - x1.z) + (e1.w - x1.w) * (e1.w - x1.w);
#pragma unroll
  for (int m = 32; m >= 1; m >>= 1) l += __shfl_xor(l, m, 64);
  if (lane == 0)
    atomicAdd(out_loss, l * (1.f / (float)((size_t)NROWS * D)));
}

// ---------------------------------------------------------------------------
extern "C" void kernel_launch(void* const* d_in, const int* in_sizes, int n_in,
                              void* d_out, int out_size, void* d_ws,
                              size_t ws_size, hipStream_t stream) {
  (void)in_sizes; (void)n_in; (void)out_size; (void)ws_size;
  const float* x     = (const float*)d_in[0];
  const float* embed = (const float*)d_in[1];

  char* ws = (char*)d_ws;
  u64*  min1  = (u64*)ws;                                  // 128 KB
  u64*  min2  = (u64*)(ws + (size_t)NROWS * 8);            // 128 KB
  float* e2   = (float*)(ws + (size_t)NROWS * 16);         // 32 KB
  int*  count = (int*)(ws + (size_t)NROWS * 16 + NCODES * 4);
  int*  list  = (int*)(ws + (size_t)NROWS * 16 + NCODES * 4 + 16);
  // packed bf16 hi/lo planes (needs ws >= ~50 MB)
  uint32_t* pack_x = (uint32_t*)(ws + (1u << 19));                  // 32 MB
  uint32_t* pack_e = (uint32_t*)(ws + (1u << 19) + ((size_t)RB * NKC * TILE_BYTES));

  float* out_q    = (float*)d_out;                 // [16384][512]
  float* out_idx  = out_q + (size_t)NROWS * D;     // [16384] as float
  float* out_loss = out_idx + NROWS;               // [1]

  hipMemsetAsync(d_ws, 0xFF, (size_t)NROWS * 16, stream);  // min1+min2
  hipMemsetAsync(count, 0, sizeof(int), stream);
  hipMemsetAsync(out_loss, 0, sizeof(float), stream);
  vq_pack_kernel<<<(NROWS + NCODES) * 64 / 256, 256, 0, stream>>>(
      x, embed, pack_x, pack_e, e2);
  vq_mfma_kernel<<<NBLK, 256, 0, stream>>>(pack_x, pack_e, e2, min1, min2);
  vq_flag_kernel<<<NROWS / 256, 256, 0, stream>>>(min1, min2, count, list);
  vq_exact_kernel<<<RCB, 256, 0, stream>>>(x, embed, e2, count, list, min1);
  vq_finish_kernel<<<NROWS / 4, 256, 0, stream>>>(x, embed, min1, out_q,
                                                  out_idx, out_loss);
}

// Round 9
// 636.511 us; speedup vs baseline: 1.1327x; 1.1327x over previous
//
#include <hip/hip_runtime.h>
#include <cstdint>
#include <cstddef>

#define D       512
#define NROWS   16384
#define NCODES  8192
#define BM      256
#define BN      256
#define NKC     16              // K-tiles (BK=32 each, hi+lo planes)
#define NBLK    2048            // (16384/256)*(8192/256)
#define EPS     0.02f
#define RCB     1024
#define TILE_BYTES 16384        // packed per (blk128,kc): [HI 8KB][LO 8KB]

typedef __attribute__((ext_vector_type(8))) short short8;  // 8 bf16
typedef __attribute__((ext_vector_type(4))) float f32x4;
typedef unsigned long long u64;
typedef __attribute__((address_space(3))) uint32_t as3_u32;
typedef __attribute__((address_space(1))) uint32_t as1_u32;

// order-preserving fp32 <-> u32 key
__device__ __forceinline__ uint32_t fkey(float f) {
  uint32_t u = __float_as_uint(f);
  return (u & 0x80000000u) ? ~u : (u | 0x80000000u);
}
__device__ __forceinline__ float unfkey(uint32_t k) {
  uint32_t u = (k & 0x80000000u) ? (k & 0x7FFFFFFFu) : ~k;
  return __uint_as_float(u);
}
// round-to-nearest bf16, returned as high-aligned fp32 bits
__device__ __forceinline__ uint32_t bfhi(float f) {
  uint32_t u = __float_as_uint(f);
  return (u + 0x7FFFu + ((u >> 16) & 1u)) & 0xFFFF0000u;
}

// ---------------------------------------------------------------------------
// Pre-pack, OUTPUT-address-ordered (round-8 pack wrote scattered 64B shards).
// Thread = one 16B hi-chunk (+ its lo partner): wave writes 2x 1KB contiguous.
// Layout per (blk128,kc): [HI 8KB][LO 8KB]; chunk (r, cp) at r*64 + cp*16,
// cp = c ^ ((r>>1)&3)  (bank swizzle used by the MFMA kernel's frag reads).
// ---------------------------------------------------------------------------
__global__ __launch_bounds__(256) void vq_pack_kernel(
    const float* __restrict__ x, const float* __restrict__ embed,
    uint32_t* __restrict__ px, uint32_t* __restrict__ pe) {
  const int oid  = blockIdx.x * 256 + threadIdx.x;       // hi-chunk id
  const bool isX = oid < NROWS * 64;                     // block-uniform split
  const int tt   = isX ? oid : oid - NROWS * 64;
  const float* src = isX ? x : embed;
  uint32_t*    dst = isX ? px : pe;

  const int tile   = tt >> 9;        // (blk,kc) tile: 512 hi-chunks each
  const int within = tt & 511;       // = r*4 + cp
  const int blk = tile >> 4, kc = tile & 15;
  const int r   = within >> 2, cpp = within & 3;
  const int c   = cpp ^ ((r >> 1) & 3);                  // source k-quarter

  const float* sp = src + (size_t)(blk * 128 + r) * D + kc * 32 + c * 8;
  const float4 v0 = *(const float4*)sp;
  const float4 v1 = *(const float4*)(sp + 4);
  const float f[8] = {v0.x, v0.y, v0.z, v0.w, v1.x, v1.y, v1.z, v1.w};
  uint32_t hi[4], lo[4];
#pragma unroll
  for (int p = 0; p < 4; ++p) {
    const uint32_t h0 = bfhi(f[2 * p]), h1 = bfhi(f[2 * p + 1]);
    hi[p] = (h0 >> 16) | (h1 & 0xFFFF0000u);
    const float l0 = f[2 * p] - __uint_as_float(h0);
    const float l1 = f[2 * p + 1] - __uint_as_float(h1);
    lo[p] = (bfhi(l0) >> 16) | (bfhi(l1) & 0xFFFF0000u);
  }
  uint32_t* dp = dst + (size_t)tile * 4096 + within * 4;   // dwords
  *(uint4*)dp          = make_uint4(hi[0], hi[1], hi[2], hi[3]);  // HI plane
  *(uint4*)(dp + 2048) = make_uint4(lo[0], lo[1], lo[2], lo[3]);  // LO plane
}

// ---------------------------------------------------------------------------
__global__ void vq_e2_kernel(const float* __restrict__ embed,
                             float* __restrict__ e2) {
  const int w    = (blockIdx.x * blockDim.x + threadIdx.x) >> 6;
  const int lane = threadIdx.x & 63;
  const float* p = embed + (size_t)w * D + lane * 8;
  const float4 a = *(const float4*)p;
  const float4 b = *(const float4*)(p + 4);
  float s = a.x * a.x + a.y * a.y + a.z * a.z + a.w * a.w +
            b.x * b.x + b.y * b.y + b.z * b.z + b.w * b.w;
#pragma unroll
  for (int m = 32; m >= 1; m >>= 1) s += __shfl_xor(s, m, 64);
  if (lane == 0) e2[w] = s;
}

// ---------------------------------------------------------------------------
// MFMA distance kernel, 256x256 tile, 512 thr (8 waves 2Mx4N, wave 128x64),
// hi/lo 3-term split (hh+hl+lh), double-buffered 2x64KB LDS, 1 block/CU.
// Schedule: ONE raw s_barrier + vmcnt(0) per K-tile (loads issued a full
// K-tile ~3700cyc early -> drain is free); body is an unbarriered region:
// 8 global_load_lds || 24 ds_read_b128 || 96 MFMA (B-frags live all tile).
// Exact global top-2 per row via the atomicMin two-cell protocol.
// ---------------------------------------------------------------------------
__global__ __launch_bounds__(512, 1) void vq_mfma_kernel(
    const uint32_t* __restrict__ xp, const uint32_t* __restrict__ ep,
    const float* __restrict__ e2g,
    u64* __restrict__ min1g, u64* __restrict__ min2g) {
  __shared__ __align__(16) char smem[131072];
  // buffer b at b*65536, 8 slices of 8KB:
  // s0 XblkA-hi s1 XblkA-lo s2 XblkB-hi s3 XblkB-lo s4..s7 same for E

  const int tid  = threadIdx.x;
  const int lane = tid & 63;
  const int w    = tid >> 6;           // 0..7
  const int wr   = (w >> 2) * 128;     // 0 / 128
  const int wcI  = w & 3;
  const int wc   = wcI * 64;

  // XCD swizzle: 4 cb per XCD (packed e slice 4x256x2KB = 2MB, L2-fits);
  // cb fast-varying -> x-panel L2 reuse.  2048 % 8 == 0 -> bijective.
  const int xcd = blockIdx.x & 7;
  const int id  = blockIdx.x >> 3;     // 0..255
  const int cb  = xcd * 4 + (id & 3);  // 0..31
  const int rb  = id >> 2;             // 0..63
  const int row0 = rb * BM;
  const int c0   = cb * BN;

  const char* xbase = (const char*)xp + (size_t)(2 * rb) * NKC * TILE_BYTES;
  const char* ebase = (const char*)ep + (size_t)(2 * cb) * NKC * TILE_BYTES;

  f32x4 acc[8][4];
#pragma unroll
  for (int i = 0; i < 8; ++i)
#pragma unroll
    for (int j = 0; j < 4; ++j) acc[i][j] = (f32x4)0.f;

  const int fr = lane & 15;
  const int cl = lane >> 4;
  const int cs = (cl ^ ((fr >> 1) & 3)) * 16;  // swizzled k-quarter byte off

#define STAGE(kc, b)                                                          \
  do {                                                                        \
    _Pragma("unroll") for (int s = 0; s < 8; ++s) {                           \
      const char* g = ((s < 4) ? xbase : ebase) +                             \
                      (size_t)((((s >> 1) & 1) * NKC + (kc)) * TILE_BYTES) +  \
                      (s & 1) * 8192 + tid * 16;                              \
      __builtin_amdgcn_global_load_lds(                                       \
          (const as1_u32*)(const void*)g,                                     \
          (as3_u32*)(void*)(smem + (b) * 65536 + s * 8192 + tid * 16),        \
          16, 0, 0);                                                          \
    }                                                                         \
  } while (0)

  STAGE(0, 0);

  int cur = 0;
  for (int t = 0; t < NKC; ++t) {
    // K-tile boundary: own loads done -> all waves' loads done.
    asm volatile("s_waitcnt vmcnt(0)" ::: "memory");
    __builtin_amdgcn_s_barrier();
    __builtin_amdgcn_sched_barrier(0);
    asm volatile("" ::: "memory");

    if (t + 1 < NKC) STAGE(t + 1, cur ^ 1);   // in flight across whole tile

    const char* sb = smem + cur * 65536;
    short8 bh[4], bl[4];
#pragma unroll
    for (int j = 0; j < 4; ++j) {
      const int erow = wc + j * 16 + fr;
      const int eoff = 32768 + (erow >> 7) * 16384 + (erow & 127) * 64 + cs;
      bh[j] = *(const short8*)(sb + eoff);
      bl[j] = *(const short8*)(sb + eoff + 8192);
    }
#pragma unroll
    for (int i = 0; i < 8; ++i) {
      const int arow = wr + i * 16 + fr;
      const int aoff = (arow >> 7) * 16384 + (arow & 127) * 64 + cs;
      const short8 ah = *(const short8*)(sb + aoff);
      const short8 al = *(const short8*)(sb + aoff + 8192);
      __builtin_amdgcn_s_setprio(1);
#pragma unroll
      for (int j = 0; j < 4; ++j) {
        acc[i][j] = __builtin_amdgcn_mfma_f32_16x16x32_bf16(ah, bh[j], acc[i][j], 0, 0, 0);
        acc[i][j] = __builtin_amdgcn_mfma_f32_16x16x32_bf16(ah, bl[j], acc[i][j], 0, 0, 0);
        acc[i][j] = __builtin_amdgcn_mfma_f32_16x16x32_bf16(al, bh[j], acc[i][j], 0, 0, 0);
      }
      __builtin_amdgcn_s_setprio(0);
    }
    cur ^= 1;
  }
#undef STAGE

  // ---- epilogue: per-row top-2 over this block's 256 codes ----
  float e2v[4];
#pragma unroll
  for (int j = 0; j < 4; ++j) e2v[j] = e2g[c0 + wc + j * 16 + fr];

  __syncthreads();                       // full drain; reuse smem
  u64 (*mb)[4][2] = (u64(*)[4][2])smem;  // [256 rows][4 col-waves][min1,min2]

#pragma unroll
  for (int i = 0; i < 8; ++i) {
#pragma unroll
    for (int r = 0; r < 4; ++r) {
      float v1 = 3.4e38f, v2 = 3.4e38f;
      int c1 = 0;
#pragma unroll
      for (int j = 0; j < 4; ++j) {
        const float s = fmaf(-2.f, acc[i][j][r], e2v[j]);
        if (s < v1) { v2 = v1; v1 = s; c1 = c0 + wc + j * 16 + fr; }
        else if (s < v2) v2 = s;
      }
      u64 p1 = ((u64)fkey(v1) << 32) | (uint32_t)c1;
      uint32_t k2 = fkey(v2);
#pragma unroll
      for (int m = 8; m >= 1; m >>= 1) {   // merge across 16-lane row-group
        const u64 o1 = __shfl_xor(p1, m, 64);
        const uint32_t o2 = __shfl_xor(k2, m, 64);
        const u64 lo_ = p1 < o1 ? p1 : o1;
        const u64 hi_ = p1 < o1 ? o1 : p1;
        uint32_t nk = k2 < o2 ? k2 : o2;
        const uint32_t hk = (uint32_t)(hi_ >> 32);
        k2 = nk < hk ? nk : hk;
        p1 = lo_;
      }
      if ((lane & 15) == 0) {
        const int lrow = wr + i * 16 + (lane >> 4) * 4 + r;
        mb[lrow][wcI][0] = p1;
        mb[lrow][wcI][1] = ((u64)k2 << 32) | 0xFFFFFFFFull;
      }
    }
  }
  __syncthreads();

  if (tid < BM) {
    u64 m1 = mb[tid][0][0], m2 = mb[tid][0][1];
#pragma unroll
    for (int q = 1; q < 4; ++q) {
      const u64 a1 = mb[tid][q][0], a2 = mb[tid][q][1];
      const u64 nm1 = m1 < a1 ? m1 : a1;
      const u64 big = m1 < a1 ? a1 : m1;
      u64 nm2 = m2 < a2 ? m2 : a2;
      nm2 = nm2 < big ? nm2 : big;
      m1 = nm1; m2 = nm2;
    }
    // lock-free global top-2 merge
    const u64 old = atomicMin(&min1g[row0 + tid], m1);
    u64 push = m1 < old ? old : m1;       // max(m1, old)
    push = m2 < push ? m2 : push;
    atomicMin(&min2g[row0 + tid], push);
  }
}

// ---------------------------------------------------------------------------
__global__ __launch_bounds__(256) void vq_flag_kernel(
    const u64* __restrict__ min1g, const u64* __restrict__ min2g,
    int* __restrict__ count, int* __restrict__ list) {
  const int row = blockIdx.x * 256 + threadIdx.x;
  const float f1 = unfkey((uint32_t)(min1g[row] >> 32));
  const float f2 = unfkey((uint32_t)(min2g[row] >> 32));
  if (!(f2 - f1 >= EPS)) {              // also catches NaN
    const int p = atomicAdd(count, 1);
    list[p] = row;
  }
}

// ---------------------------------------------------------------------------
__global__ __launch_bounds__(256) void vq_exact_kernel(
    const float* __restrict__ x, const float* __restrict__ embed,
    const float* __restrict__ e2g, const int* __restrict__ count,
    const int* __restrict__ list, u64* __restrict__ min1g) {
  const int nItems = (*count) * 32;
  __shared__ u64 wbest[4];
  const int lane = threadIdx.x & 63;
  const int wv   = threadIdx.x >> 6;

  for (int it = blockIdx.x; it < nItems; it += RCB) {
    const int row   = list[it >> 5];
    const int cbase = (it & 31) * 256 + wv * 64;

    const float* xpr = x + (size_t)row * D + lane * 8;
    const float4 xa = *(const float4*)xpr;
    const float4 xb = *(const float4*)(xpr + 4);

    float bv = 3.4e38f;
    int   bi = 0;
    for (int i = 0; i < 64; ++i) {
      const int c = cbase + i;
      const float* epr = embed + (size_t)c * D + lane * 8;
      const float4 ea = *(const float4*)epr;
      const float4 eb = *(const float4*)(epr + 4);
      float p = xa.x * ea.x + xa.y * ea.y + xa.z * ea.z + xa.w * ea.w +
                xb.x * eb.x + xb.y * eb.y + xb.z * eb.z + xb.w * eb.w;
#pragma unroll
      for (int m = 32; m >= 1; m >>= 1) p += __shfl_xor(p, m, 64);
      const float s = fmaf(-2.f, p, e2g[c]);
      if (s < bv) { bv = s; bi = c; }
    }
    const u64 pk = ((u64)fkey(bv) << 32) | (uint32_t)bi;
    if (lane == 0) wbest[wv] = pk;
    __syncthreads();
    if (threadIdx.x == 0) {
      u64 m = wbest[0];
#pragma unroll
      for (int q = 1; q < 4; ++q) m = wbest[q] < m ? wbest[q] : m;
      atomicMin(&min1g[row], m);
    }
    __syncthreads();
  }
}

// ---------------------------------------------------------------------------
__global__ void vq_finish_kernel(const float* __restrict__ x,
                                 const float* __restrict__ embed,
                                 const u64* __restrict__ min1g,
                                 float* __restrict__ out_q,
                                 float* __restrict__ out_idx,
                                 float* __restrict__ out_loss) {
  const int row  = blockIdx.x * 4 + (threadIdx.x >> 6);
  const int lane = threadIdx.x & 63;
  const int idx  = (int)(min1g[row] & 0xFFFFFFFFull);
  if (lane == 0) out_idx[row] = (float)idx;

  const float* ep = embed + (size_t)idx * D + lane * 8;
  const float* xp = x + (size_t)row * D + lane * 8;
  float* qp       = out_q + (size_t)row * D + lane * 8;

  const float4 e0 = *(const float4*)ep;
  const float4 e1 = *(const float4*)(ep + 4);
  const float4 x0 = *(const float4*)xp;
  const float4 x1 = *(const float4*)(xp + 4);
  *(float4*)qp       = e0;   // x + sg(q - x) == q numerically
  *(float4*)(qp + 4) = e1;

  float l = (e0.x - x0.x) * (e0.x - x0.x) + (e0.y - x0.y) * (e0.y - x0.y) +
            (e0.z - x0.z) * (e0.z - x0.z) + (e0.w - x0.w) * (e0.w - x0.w) +
            (e1.x - x1.x) * (e1.x - x1.x) + (e1.y - x1.y) * (e1.y - x1.y) +
            (e1.z - x1.z) * (e1.z - x1.z) + (e1.w - x1.w) * (e1.w - x1.w);
#pragma unroll
  for (int m = 32; m >= 1; m >>= 1) l += __shfl_xor(l, m, 64);
  if (lane == 0)
    atomicAdd(out_loss, l * (1.f / (float)((size_t)NROWS * D)));
}

// ---------------------------------------------------------------------------
extern "C" void kernel_launch(void* const* d_in, const int* in_sizes, int n_in,
                              void* d_out, int out_size, void* d_ws,
                              size_t ws_size, hipStream_t stream) {
  (void)in_sizes; (void)n_in; (void)out_size; (void)ws_size;
  const float* x     = (const float*)d_in[0];
  const float* embed = (const float*)d_in[1];

  char* ws = (char*)d_ws;
  u64*  min1  = (u64*)ws;                                  // 128 KB
  u64*  min2  = (u64*)(ws + (size_t)NROWS * 8);            // 128 KB
  float* e2   = (float*)(ws + (size_t)NROWS * 16);         // 32 KB
  int*  count = (int*)(ws + (size_t)NROWS * 16 + NCODES * 4);
  int*  list  = (int*)(ws + (size_t)NROWS * 16 + NCODES * 4 + 16);
  // packed bf16 hi/lo planes (needs ws >= ~50 MB)
  uint32_t* pack_x = (uint32_t*)(ws + (1u << 19));                  // 32 MB
  uint32_t* pack_e = (uint32_t*)(ws + (1u << 19) +
                                 ((size_t)(NROWS / 128) * NKC * TILE_BYTES));

  float* out_q    = (float*)d_out;                 // [16384][512]
  float* out_idx  = out_q + (size_t)NROWS * D;     // [16384] as float
  float* out_loss = out_idx + NROWS;               // [1]

  hipMemsetAsync(d_ws, 0xFF, (size_t)NROWS * 16, stream);  // min1+min2
  hipMemsetAsync(count, 0, sizeof(int), stream);
  hipMemsetAsync(out_loss, 0, sizeof(float), stream);
  vq_pack_kernel<<<(NROWS + NCODES) * 64 / 256, 256, 0, stream>>>(
      x, embed, pack_x, pack_e);
  vq_e2_kernel<<<NCODES / 4, 256, 0, stream>>>(embed, e2);
  vq_mfma_kernel<<<NBLK, 512, 0, stream>>>(pack_x, pack_e, e2, min1, min2);
  vq_flag_kernel<<<NROWS / 256, 256, 0, stream>>>(min1, min2, count, list);
  vq_exact_kernel<<<RCB, 256, 0, stream>>>(x, embed, e2, count, list, min1);
  vq_finish_kernel<<<NROWS / 4, 256, 0, stream>>>(x, embed, min1, out_q,
                                                  out_idx, out_loss);
}